// Round 9
// baseline (182.286 us; speedup 1.0000x reference)
//
#include <hip/hip_runtime.h>

// Problem constants: B=8, N=256, D=300, P=128, V=50001
#define NB 8
#define NN 256
#define DD 300
#define PP 128
#define NC 512                          // concat cols = [Wl|Wr|Ws1|We1]
#define OFF_S (NB * NN * NN)            // 524288  start-head element offset
#define OFF_E (NB * NN * NN + NB * NN)  // 526336  end-head element offset

typedef unsigned short u16;
typedef unsigned int   u32;

__device__ __forceinline__ float bf2f(u16 u) {
    union { u32 i; float f; } v;
    v.i = ((u32)u) << 16;
    return v.f;
}
__device__ __forceinline__ u16 f2bf(float f) {
    union { float f; u32 i; } v;
    v.f = f;
    u32 lsb = (v.i >> 16) & 1u;
    v.i += 0x7fffu + lsb;   // round-to-nearest-even
    return (u16)(v.i >> 16);
}

template<bool BF>
__device__ __forceinline__ float4 ld4(const void* base, int idx) {
    if (BF) {
        ushort4 e = *(const ushort4*)((const u16*)base + idx);
        return make_float4(bf2f(e.x), bf2f(e.y), bf2f(e.z), bf2f(e.w));
    } else {
        return *(const float4*)((const float*)base + idx);
    }
}
template<bool BF>
__device__ __forceinline__ float ld1(const void* base, int idx) {
    return BF ? bf2f(((const u16*)base)[idx]) : ((const float*)base)[idx];
}
template<bool BF>
__device__ __forceinline__ void st1(void* base, int idx, float v) {
    if (BF) ((u16*)base)[idx] = f2bf(v);
    else    ((float*)base)[idx] = v;
}
template<bool BF>
__device__ __forceinline__ void st4(void* base, int idx, float4 v) {
    if (BF) {
        ushort4 o = make_ushort4(f2bf(v.x), f2bf(v.y), f2bf(v.z), f2bf(v.w));
        *(ushort4*)((u16*)base + idx) = o;
    } else {
        *(float4*)((float*)base + idx) = v;
    }
}
// acc += relu(l + r) * w, componentwise over l (r, w scalar)
__device__ __forceinline__ float4 rfma4(float4 l, float r, float w, float4 a) {
    a.x = fmaf(fmaxf(l.x + r, 0.f), w, a.x);
    a.y = fmaf(fmaxf(l.y + r, 0.f), w, a.y);
    a.z = fmaf(fmaxf(l.z + r, 0.f), w, a.z);
    a.w = fmaf(fmaxf(l.w + r, 0.f), w, a.w);
    return a;
}

// ---------------------------------------------------------------------------
// Detector (verbatim from passing R2/R4/R7/R8).
// ---------------------------------------------------------------------------
extern "C" __global__ void detect_kernel(const u32* __restrict__ embU,
                                         int* __restrict__ flag) {
    int lane = threadIdx.x;  // 64 threads
    int cnt = 0;
    for (int i = lane; i < 256; i += 64) {
        u32 w = embU[i];
        union { u32 u; float f; } v;
        v.u = (w & 0xFFFFu) << 16;
        float a = fabsf(v.f);
        if (a == 0.f || (a >= 0.00390625f && a <= 256.f)) cnt++;
    }
    #pragma unroll
    for (int off = 32; off; off >>= 1) cnt += __shfl_down(cnt, off, 64);
    if (lane == 0) *flag = (cnt >= 128) ? 1 : 0;
}

// ---------------------------------------------------------------------------
// prep: blocks 0..15  -> WTf[k][c] = (float)Wcat[c][k]   (R7-passing code)
//       blocks 16..47 -> xf[t][k]  = (float)emb[sent[t]][k]  (64 tokens each)
// xf enables tok to read activations via uniform s_load (scalar pipe).
// ---------------------------------------------------------------------------
template<bool BF>
__device__ __forceinline__ void prep_body(
    const void* __restrict__ Wl, const void* __restrict__ Wr,
    const void* __restrict__ Ws1, const void* __restrict__ We1,
    const int* __restrict__ sent, const void* __restrict__ emb,
    float* __restrict__ WTf, float* __restrict__ xf, float (*tile)[301])
{
    const int tid = threadIdx.x;

    if (blockIdx.x < 16) {
        const int c0 = blockIdx.x * 32;
        for (int e = tid; e < 32 * 75; e += 256) {       // row-major reads
            int r = e / 75;
            int q = e - r * 75;
            int c = c0 + r;
            const void* src = (c < 128) ? Wl : (c < 256) ? Wr
                            : (c < 384) ? Ws1 : We1;
            float4 f = ld4<BF>(src, (c & 127) * DD + 4 * q);
            tile[r][4 * q + 0] = f.x;
            tile[r][4 * q + 1] = f.y;
            tile[r][4 * q + 2] = f.z;
            tile[r][4 * q + 3] = f.w;
        }
        __syncthreads();
        for (int e = tid; e < 300 * 32; e += 256) {      // k-major writes
            int k = e >> 5;
            int c = e & 31;
            WTf[(size_t)k * NC + c0 + c] = tile[c][k];
        }
    } else {
        const int t0g = (blockIdx.x - 16) * 64;
        for (int e = tid; e < 64 * DD; e += 256) {
            int t = e / DD;
            int k = e - t * DD;
            int idx = sent[t0g + t];
            xf[(size_t)(t0g + t) * DD + k] = ld1<BF>(emb, idx * DD + k);
        }
    }
}

extern "C" __global__ void __launch_bounds__(256)
prep_kernel(const void* __restrict__ Wl, const void* __restrict__ Wr,
            const void* __restrict__ Ws1, const void* __restrict__ We1,
            const int* __restrict__ sent, const void* __restrict__ emb,
            float* __restrict__ WTf, float* __restrict__ xf,
            const int* __restrict__ flag)
{
    __shared__ float tile[32][301];
    if (*flag) prep_body<true >(Wl, Wr, Ws1, We1, sent, emb, WTf, xf, tile);
    else       prep_body<false>(Wl, Wr, Ws1, We1, sent, emb, WTf, xf, tile);
}

// ---------------------------------------------------------------------------
// tok v3: zero-LDS GEMV. Grid 256 blocks x 256 thr; block = 8 tokens.
// half = tid>>7 -> tokens t0+4h..t0+4h+3; thread owns cols col4..col4+3
// (col4 = (tid&127)*4, covers all 512 concat cols per 128-thread half).
// Per k: one coalesced float4 weight load (1KB/wave) + 4 uniform s_loads
// of x (scalar pipe, SGPR broadcast) + 16 FMAs. No LDS in the main loop.
// ---------------------------------------------------------------------------
template<bool BF>
__device__ __forceinline__ void tok_body(
    const float* __restrict__ WTf, const float* __restrict__ xf,
    const void* __restrict__ bl,
    const void* __restrict__ bs1, const void* __restrict__ Ws2,
    const void* __restrict__ bs2,
    const void* __restrict__ be1, const void* __restrict__ We2,
    const void* __restrict__ be2,
    float* __restrict__ leftT, float* __restrict__ rightW,
    void* __restrict__ out)
{
    const int tid   = threadIdx.x;
    const int t0    = blockIdx.x * 8;
    const int half  = tid >> 7;
    const int l127  = tid & 127;
    const int col4  = l127 * 4;
    const int tbase = t0 + 4 * half;

    const float* x0 = xf + (size_t)(tbase + 0) * DD;   // uniform pointers
    const float* x1 = xf + (size_t)(tbase + 1) * DD;
    const float* x2 = xf + (size_t)(tbase + 2) * DD;
    const float* x3 = xf + (size_t)(tbase + 3) * DD;
    const float* wrow = WTf + col4;

    float a0[4] = {0,0,0,0}, a1[4] = {0,0,0,0};
    float a2[4] = {0,0,0,0}, a3[4] = {0,0,0,0};   // acc[token][col]

    #pragma unroll 4
    for (int k = 0; k < DD; ++k) {
        float4 w = *(const float4*)(wrow + (size_t)k * NC);  // coalesced b128
        float s0 = x0[k], s1 = x1[k], s2 = x2[k], s3 = x3[k]; // s_load
        a0[0] = fmaf(w.x, s0, a0[0]); a0[1] = fmaf(w.y, s0, a0[1]);
        a0[2] = fmaf(w.z, s0, a0[2]); a0[3] = fmaf(w.w, s0, a0[3]);
        a1[0] = fmaf(w.x, s1, a1[0]); a1[1] = fmaf(w.y, s1, a1[1]);
        a1[2] = fmaf(w.z, s1, a1[2]); a1[3] = fmaf(w.w, s1, a1[3]);
        a2[0] = fmaf(w.x, s2, a2[0]); a2[1] = fmaf(w.y, s2, a2[1]);
        a2[2] = fmaf(w.z, s2, a2[2]); a2[3] = fmaf(w.w, s2, a2[3]);
        a3[0] = fmaf(w.x, s3, a3[0]); a3[1] = fmaf(w.y, s3, a3[1]);
        a3[2] = fmaf(w.z, s3, a3[2]); a3[3] = fmaf(w.w, s3, a3[3]);
    }

    const int m = l127 >> 5;       // matrix id: 0 Wl, 1 Wr, 2 Ws1, 3 We1
    const int p = col4 & 127;      // row within matrix, %4==0

    if (m == 0) {                  // left -> leftT[b][p][j], + bl
        float b[4];
        #pragma unroll
        for (int r = 0; r < 4; ++r) b[r] = ld1<BF>(bl, p + r);
        const int bb = tbase >> 8;
        #pragma unroll
        for (int tt = 0; tt < 4; ++tt) {
            const int jj = (tbase + tt) & 255;
            float* acc = (tt == 0) ? a0 : (tt == 1) ? a1 : (tt == 2) ? a2 : a3;
            #pragma unroll
            for (int r = 0; r < 4; ++r)
                leftT[((size_t)bb * PP + p + r) * NN + jj] = acc[r] + b[r];
        }
    } else if (m == 1) {           // right -> rightW[t][p] (float4)
        #pragma unroll
        for (int tt = 0; tt < 4; ++tt) {
            float* acc = (tt == 0) ? a0 : (tt == 1) ? a1 : (tt == 2) ? a2 : a3;
            *(float4*)(rightW + (size_t)(tbase + tt) * PP + p) =
                make_float4(acc[0], acc[1], acc[2], acc[3]);
        }
    } else {                       // start (m==2) / end (m==3) heads
        const void* h1 = (m == 2) ? bs1 : be1;
        const void* h2 = (m == 2) ? Ws2 : We2;
        const void* h3 = (m == 2) ? bs2 : be2;
        float b1[4], w2[4];
        #pragma unroll
        for (int r = 0; r < 4; ++r) {
            b1[r] = ld1<BF>(h1, p + r);
            w2[r] = ld1<BF>(h2, p + r);
        }
        float v[4];
        #pragma unroll
        for (int tt = 0; tt < 4; ++tt) {
            float* acc = (tt == 0) ? a0 : (tt == 1) ? a1 : (tt == 2) ? a2 : a3;
            float s = 0.f;
            #pragma unroll
            for (int r = 0; r < 4; ++r)
                s += fmaxf(acc[r] + b1[r], 0.f) * w2[r];
            v[tt] = s;
        }
        // Reduce over the 32-thread group (one 32-lane shuffle segment).
        #pragma unroll
        for (int off = 16; off; off >>= 1) {
            #pragma unroll
            for (int tt = 0; tt < 4; ++tt)
                v[tt] += __shfl_down(v[tt], off, 32);
        }
        if ((l127 & 31) == 0) {
            float b2 = ld1<BF>(h3, 0);
            int base = (m == 2) ? OFF_S : OFF_E;
            #pragma unroll
            for (int tt = 0; tt < 4; ++tt)
                st1<BF>(out, base + tbase + tt, v[tt] + b2);
        }
    }
}

extern "C" __global__ void __launch_bounds__(256)
tok_kernel(const float* __restrict__ WTf, const float* __restrict__ xf,
           const void* __restrict__ bl,
           const void* __restrict__ bs1, const void* __restrict__ Ws2,
           const void* __restrict__ bs2,
           const void* __restrict__ be1, const void* __restrict__ We2,
           const void* __restrict__ be2,
           float* __restrict__ leftT, float* __restrict__ rightW,
           void* __restrict__ out, const int* __restrict__ flag)
{
    if (*flag) {
        tok_body<true >(WTf, xf, bl, bs1, Ws2, bs2, be1, We2, be2,
                        leftT, rightW, out);
    } else {
        tok_body<false>(WTf, xf, bl, bs1, Ws2, bs2, be1, We2, be2,
                        leftT, rightW, out);
    }
}

// ---------------------------------------------------------------------------
// big v2 (verbatim from passing R8): lane owns 4 j's, 4 i-accumulators,
// wave owns a p-quarter, cross-wave LDS reduction.
// ---------------------------------------------------------------------------
template<bool BF>
__device__ __forceinline__ void big_body(
    const float* __restrict__ leftT, const float* __restrict__ rightW,
    const void* __restrict__ Wo, const void* __restrict__ bo,
    void* __restrict__ outB,
    float (*sR)[128], float* sWo, float4 (*red4)[64][4])
{
    const int tid = threadIdx.x;
    const int b   = blockIdx.x >> 6;
    const int i0  = (blockIdx.x & 63) << 2;

    if (tid < 128) sWo[tid] = ld1<BF>(Wo, tid);
    for (int c = tid; c < 512; c += 256) {
        int i = c >> 7, pp = c & 127;
        sR[i][pp] = rightW[((size_t)(b * NN + i0 + i)) * PP + pp];
    }
    __syncthreads();

    const int w    = tid >> 6;          // p-quarter
    const int lane = tid & 63;
    const int j4   = lane << 2;
    const float* lp = leftT + (size_t)b * PP * NN + j4;

    float4 A0 = {0.f, 0.f, 0.f, 0.f}, A1 = A0, A2 = A0, A3 = A0;
    const int pbase = w * 32;
    #pragma unroll
    for (int g = 0; g < 8; ++g) {
        const int p = pbase + g * 4;
        float4 wo = *(const float4*)&sWo[p];       // broadcast b128
        float4 r0 = *(const float4*)&sR[0][p];
        float4 r1 = *(const float4*)&sR[1][p];
        float4 r2 = *(const float4*)&sR[2][p];
        float4 r3 = *(const float4*)&sR[3][p];
        const float* lpp = lp + (size_t)p * NN;
        float4 l0 = *(const float4*)(lpp);         // coalesced b128
        float4 l1 = *(const float4*)(lpp + NN);
        float4 l2 = *(const float4*)(lpp + 2 * NN);
        float4 l3 = *(const float4*)(lpp + 3 * NN);
        A0 = rfma4(l0, r0.x, wo.x, A0);
        A1 = rfma4(l0, r1.x, wo.x, A1);
        A2 = rfma4(l0, r2.x, wo.x, A2);
        A3 = rfma4(l0, r3.x, wo.x, A3);
        A0 = rfma4(l1, r0.y, wo.y, A0);
        A1 = rfma4(l1, r1.y, wo.y, A1);
        A2 = rfma4(l1, r2.y, wo.y, A2);
        A3 = rfma4(l1, r3.y, wo.y, A3);
        A0 = rfma4(l2, r0.z, wo.z, A0);
        A1 = rfma4(l2, r1.z, wo.z, A1);
        A2 = rfma4(l2, r2.z, wo.z, A2);
        A3 = rfma4(l2, r3.z, wo.z, A3);
        A0 = rfma4(l3, r0.w, wo.w, A0);
        A1 = rfma4(l3, r1.w, wo.w, A1);
        A2 = rfma4(l3, r2.w, wo.w, A2);
        A3 = rfma4(l3, r3.w, wo.w, A3);
    }

    red4[w][lane][0] = A0;
    red4[w][lane][1] = A1;
    red4[w][lane][2] = A2;
    red4[w][lane][3] = A3;
    __syncthreads();

    if (tid < 64) {
        float bov = ld1<BF>(bo, 0);
        #pragma unroll
        for (int i = 0; i < 4; ++i) {
            float4 s0 = red4[0][tid][i];
            float4 s1 = red4[1][tid][i];
            float4 s2 = red4[2][tid][i];
            float4 s3 = red4[3][tid][i];
            float4 s;
            s.x = s0.x + s1.x + s2.x + s3.x + bov;
            s.y = s0.y + s1.y + s2.y + s3.y + bov;
            s.z = s0.z + s1.z + s2.z + s3.z + bov;
            s.w = s0.w + s1.w + s2.w + s3.w + bov;
            st4<BF>(outB, (int)(((size_t)(b * NN + i0 + i)) * NN) + tid * 4, s);
        }
    }
}

extern "C" __global__ void __launch_bounds__(256)
big_kernel(const float* __restrict__ leftT, const float* __restrict__ rightW,
           const void* __restrict__ Wo, const void* __restrict__ bo,
           void* __restrict__ outB, const int* __restrict__ flag)
{
    __shared__ float sR[4][128];
    __shared__ float sWo[128];
    __shared__ float4 red4[4][64][4];
    if (*flag) big_body<true >(leftT, rightW, Wo, bo, outB, sR, sWo, red4);
    else       big_body<false>(leftT, rightW, Wo, bo, outB, sR, sWo, red4);
}

extern "C" void kernel_launch(void* const* d_in, const int* in_sizes, int n_in,
                              void* d_out, int out_size, void* d_ws, size_t ws_size,
                              hipStream_t stream) {
    const int*  sent = (const int*)d_in[0];
    const void* emb  = d_in[1];
    const void* Wl   = d_in[2];
    const void* bl   = d_in[3];
    const void* Wr   = d_in[4];
    const void* Wo   = d_in[5];
    const void* bo   = d_in[6];
    const void* Ws1  = d_in[7];
    const void* bs1  = d_in[8];
    const void* Ws2  = d_in[9];
    const void* bs2  = d_in[10];
    const void* We1  = d_in[11];
    const void* be1  = d_in[12];
    const void* We2  = d_in[13];
    const void* be2  = d_in[14];

    // ws layout: passing R7/R8 prefix [flag 4B pad 1KB][leftT 1MB]
    // [rightW 1MB][WTf 600KB], then xf[2048][300] f32 (2.4MB) appended.
    int*   flag   = (int*)d_ws;
    float* leftT  = (float*)((char*)d_ws + 1024);
    float* rightW = leftT + (size_t)NB * PP * NN;
    float* WTf    = rightW + (size_t)NB * NN * PP;
    float* xf     = WTf + (size_t)DD * NC;

    hipLaunchKernelGGL(detect_kernel, dim3(1), dim3(64), 0, stream,
                       (const u32*)emb, flag);
    hipLaunchKernelGGL(prep_kernel, dim3(48), dim3(256), 0, stream,
                       Wl, Wr, Ws1, We1, sent, emb, WTf, xf, flag);
    hipLaunchKernelGGL(tok_kernel, dim3(256), dim3(256), 0, stream,
                       WTf, xf, bl, bs1, Ws2, bs2, be1, We2, be2,
                       leftT, rightW, d_out, flag);
    hipLaunchKernelGGL(big_kernel, dim3(512), dim3(256), 0, stream,
                       leftT, rightW, Wo, bo, d_out, flag);
}

// Round 10
// 180.582 us; speedup vs baseline: 1.0094x; 1.0094x over previous
//
#include <hip/hip_runtime.h>

// Problem constants: B=8, N=256, D=300, P=128, V=50001
#define NB 8
#define NN 256
#define DD 300
#define PP 128
#define NC 512                          // concat cols = [Wl|Wr|Ws1|We1]
#define OFF_S (NB * NN * NN)            // 524288  start-head element offset
#define OFF_E (NB * NN * NN + NB * NN)  // 526336  end-head element offset

typedef unsigned short u16;
typedef unsigned int   u32;

__device__ __forceinline__ float bf2f(u16 u) {
    union { u32 i; float f; } v;
    v.i = ((u32)u) << 16;
    return v.f;
}
__device__ __forceinline__ u16 f2bf(float f) {
    union { float f; u32 i; } v;
    v.f = f;
    u32 lsb = (v.i >> 16) & 1u;
    v.i += 0x7fffu + lsb;   // round-to-nearest-even
    return (u16)(v.i >> 16);
}

template<bool BF>
__device__ __forceinline__ float4 ld4(const void* base, int idx) {
    if (BF) {
        ushort4 e = *(const ushort4*)((const u16*)base + idx);
        return make_float4(bf2f(e.x), bf2f(e.y), bf2f(e.z), bf2f(e.w));
    } else {
        return *(const float4*)((const float*)base + idx);
    }
}
template<bool BF>
__device__ __forceinline__ float ld1(const void* base, int idx) {
    return BF ? bf2f(((const u16*)base)[idx]) : ((const float*)base)[idx];
}
template<bool BF>
__device__ __forceinline__ void st1(void* base, int idx, float v) {
    if (BF) ((u16*)base)[idx] = f2bf(v);
    else    ((float*)base)[idx] = v;
}
template<bool BF>
__device__ __forceinline__ void st4(void* base, int idx, float4 v) {
    if (BF) {
        ushort4 o = make_ushort4(f2bf(v.x), f2bf(v.y), f2bf(v.z), f2bf(v.w));
        *(ushort4*)((u16*)base + idx) = o;
    } else {
        *(float4*)((float*)base + idx) = v;
    }
}
// acc += relu(l + r) * w, componentwise over l (r, w scalar)
__device__ __forceinline__ float4 rfma4(float4 l, float r, float w, float4 a) {
    a.x = fmaf(fmaxf(l.x + r, 0.f), w, a.x);
    a.y = fmaf(fmaxf(l.y + r, 0.f), w, a.y);
    a.z = fmaf(fmaxf(l.z + r, 0.f), w, a.z);
    a.w = fmaf(fmaxf(l.w + r, 0.f), w, a.w);
    return a;
}

// ---------------------------------------------------------------------------
// Detector (verbatim from passing R2/R4/R7/R8/R9).
// ---------------------------------------------------------------------------
extern "C" __global__ void detect_kernel(const u32* __restrict__ embU,
                                         int* __restrict__ flag) {
    int lane = threadIdx.x;  // 64 threads
    int cnt = 0;
    for (int i = lane; i < 256; i += 64) {
        u32 w = embU[i];
        union { u32 u; float f; } v;
        v.u = (w & 0xFFFFu) << 16;
        float a = fabsf(v.f);
        if (a == 0.f || (a >= 0.00390625f && a <= 256.f)) cnt++;
    }
    #pragma unroll
    for (int off = 32; off; off >>= 1) cnt += __shfl_down(cnt, off, 64);
    if (lane == 0) *flag = (cnt >= 128) ? 1 : 0;
}

// ---------------------------------------------------------------------------
// prep (verbatim from passing R9):
//   blocks 0..15  -> WTf[k][c] = (float)Wcat[c][k]
//   blocks 16..47 -> xf[t][k]  = (float)emb[sent[t]][k]
// ---------------------------------------------------------------------------
template<bool BF>
__device__ __forceinline__ void prep_body(
    const void* __restrict__ Wl, const void* __restrict__ Wr,
    const void* __restrict__ Ws1, const void* __restrict__ We1,
    const int* __restrict__ sent, const void* __restrict__ emb,
    float* __restrict__ WTf, float* __restrict__ xf, float (*tile)[301])
{
    const int tid = threadIdx.x;

    if (blockIdx.x < 16) {
        const int c0 = blockIdx.x * 32;
        for (int e = tid; e < 32 * 75; e += 256) {       // row-major reads
            int r = e / 75;
            int q = e - r * 75;
            int c = c0 + r;
            const void* src = (c < 128) ? Wl : (c < 256) ? Wr
                            : (c < 384) ? Ws1 : We1;
            float4 f = ld4<BF>(src, (c & 127) * DD + 4 * q);
            tile[r][4 * q + 0] = f.x;
            tile[r][4 * q + 1] = f.y;
            tile[r][4 * q + 2] = f.z;
            tile[r][4 * q + 3] = f.w;
        }
        __syncthreads();
        for (int e = tid; e < 300 * 32; e += 256) {      // k-major writes
            int k = e >> 5;
            int c = e & 31;
            WTf[(size_t)k * NC + c0 + c] = tile[c][k];
        }
    } else {
        const int t0g = (blockIdx.x - 16) * 64;
        for (int e = tid; e < 64 * DD; e += 256) {
            int t = e / DD;
            int k = e - t * DD;
            int idx = sent[t0g + t];
            xf[(size_t)(t0g + t) * DD + k] = ld1<BF>(emb, idx * DD + k);
        }
    }
}

extern "C" __global__ void __launch_bounds__(256)
prep_kernel(const void* __restrict__ Wl, const void* __restrict__ Wr,
            const void* __restrict__ Ws1, const void* __restrict__ We1,
            const int* __restrict__ sent, const void* __restrict__ emb,
            float* __restrict__ WTf, float* __restrict__ xf,
            const int* __restrict__ flag)
{
    __shared__ float tile[32][301];
    if (*flag) prep_body<true >(Wl, Wr, Ws1, We1, sent, emb, WTf, xf, tile);
    else       prep_body<false>(Wl, Wr, Ws1, We1, sent, emb, WTf, xf, tile);
}

// ---------------------------------------------------------------------------
// tok v4: R8's passing shape (grid 512, 4 tokens/block, thread owns concat
// cols (2*tid, 2*tid+1), wave = matrix) with ONE change: activations come
// from xf via BLOCK-UNIFORM pointers (pure blockIdx arithmetic) -> the
// compiler lowers x0[k]..x3[k] to s_load on the scalar pipe (SGPR
// broadcast, batched dwordx4 under unroll-4). Zero LDS in the kernel;
// per k: 1 coalesced float2 VMEM + 8 FMAs.
// ---------------------------------------------------------------------------
template<bool BF>
__device__ __forceinline__ void tok_body(
    const float* __restrict__ WTf, const float* __restrict__ xf,
    const void* __restrict__ bl,
    const void* __restrict__ bs1, const void* __restrict__ Ws2,
    const void* __restrict__ bs2,
    const void* __restrict__ be1, const void* __restrict__ We2,
    const void* __restrict__ be2,
    float* __restrict__ leftT, float* __restrict__ rightW,
    void* __restrict__ out)
{
    const int tid = threadIdx.x;
    const int t0  = blockIdx.x * 4;

    // Block-uniform activation pointers -> scalar loads.
    const float* x0 = xf + (size_t)(t0 + 0) * DD;
    const float* x1 = xf + (size_t)(t0 + 1) * DD;
    const float* x2 = xf + (size_t)(t0 + 2) * DD;
    const float* x3 = xf + (size_t)(t0 + 3) * DD;

    float a0[4], a1[4];                  // acc[token] for cols p0, p1
    #pragma unroll
    for (int t = 0; t < 4; ++t) { a0[t] = 0.f; a1[t] = 0.f; }

    const float* wp = WTf + 2 * tid;
    #pragma unroll 4
    for (int k = 0; k < DD; ++k) {
        float2 w  = *(const float2*)(wp + (size_t)k * NC);  // coalesced b64
        float s0 = x0[k], s1 = x1[k], s2 = x2[k], s3 = x3[k]; // s_load
        a0[0] = fmaf(s0, w.x, a0[0]); a1[0] = fmaf(s0, w.y, a1[0]);
        a0[1] = fmaf(s1, w.x, a0[1]); a1[1] = fmaf(s1, w.y, a1[1]);
        a0[2] = fmaf(s2, w.x, a0[2]); a1[2] = fmaf(s2, w.y, a1[2]);
        a0[3] = fmaf(s3, w.x, a0[3]); a1[3] = fmaf(s3, w.y, a1[3]);
    }

    // Epilogue (verbatim from passing R8).
    const int wv = tid >> 6;     // matrix id (wave-uniform)
    const int l  = tid & 63;
    const int p0 = 2 * l, p1 = p0 + 1;

    if (wv == 0) {               // left = x@Wl.T + bl -> leftT[b][p][j]
        float b0 = ld1<BF>(bl, p0), b1 = ld1<BF>(bl, p1);
        #pragma unroll
        for (int t = 0; t < 4; ++t) {
            int tg = t0 + t, bb = tg >> 8, jj = tg & 255;
            leftT[((size_t)bb * PP + p0) * NN + jj] = a0[t] + b0;
            leftT[((size_t)bb * PP + p1) * NN + jj] = a1[t] + b1;
        }
    } else if (wv == 1) {        // right = x@Wr.T -> rightW[t][p]
        #pragma unroll
        for (int t = 0; t < 4; ++t) {
            rightW[(size_t)(t0 + t) * PP + p0] = a0[t];
            rightW[(size_t)(t0 + t) * PP + p1] = a1[t];
        }
    } else {                     // start (wv==2) / end (wv==3) heads
        const void* h1 = (wv == 2) ? bs1 : be1;
        const void* h2 = (wv == 2) ? Ws2 : We2;
        const void* h3 = (wv == 2) ? bs2 : be2;
        float b0 = ld1<BF>(h1, p0), b1 = ld1<BF>(h1, p1);
        float w0 = ld1<BF>(h2, p0), w1 = ld1<BF>(h2, p1);
        float v[4];
        #pragma unroll
        for (int t = 0; t < 4; ++t)
            v[t] = fmaxf(a0[t] + b0, 0.f) * w0 + fmaxf(a1[t] + b1, 0.f) * w1;
        #pragma unroll
        for (int off = 32; off; off >>= 1) {
            #pragma unroll
            for (int t = 0; t < 4; ++t) v[t] += __shfl_down(v[t], off, 64);
        }
        if (l == 0) {
            float b2 = ld1<BF>(h3, 0);
            int base = (wv == 2) ? OFF_S : OFF_E;
            #pragma unroll
            for (int t = 0; t < 4; ++t)
                st1<BF>(out, base + t0 + t, v[t] + b2);
        }
    }
}

extern "C" __global__ void __launch_bounds__(256)
tok_kernel(const float* __restrict__ WTf, const float* __restrict__ xf,
           const void* __restrict__ bl,
           const void* __restrict__ bs1, const void* __restrict__ Ws2,
           const void* __restrict__ bs2,
           const void* __restrict__ be1, const void* __restrict__ We2,
           const void* __restrict__ be2,
           float* __restrict__ leftT, float* __restrict__ rightW,
           void* __restrict__ out, const int* __restrict__ flag)
{
    if (*flag) {
        tok_body<true >(WTf, xf, bl, bs1, Ws2, bs2, be1, We2, be2,
                        leftT, rightW, out);
    } else {
        tok_body<false>(WTf, xf, bl, bs1, Ws2, bs2, be1, We2, be2,
                        leftT, rightW, out);
    }
}

// ---------------------------------------------------------------------------
// big v2 (verbatim from passing R8/R9): lane owns 4 j's, 4 i-accumulators,
// wave owns a p-quarter, cross-wave LDS reduction.
// ---------------------------------------------------------------------------
template<bool BF>
__device__ __forceinline__ void big_body(
    const float* __restrict__ leftT, const float* __restrict__ rightW,
    const void* __restrict__ Wo, const void* __restrict__ bo,
    void* __restrict__ outB,
    float (*sR)[128], float* sWo, float4 (*red4)[64][4])
{
    const int tid = threadIdx.x;
    const int b   = blockIdx.x >> 6;
    const int i0  = (blockIdx.x & 63) << 2;

    if (tid < 128) sWo[tid] = ld1<BF>(Wo, tid);
    for (int c = tid; c < 512; c += 256) {
        int i = c >> 7, pp = c & 127;
        sR[i][pp] = rightW[((size_t)(b * NN + i0 + i)) * PP + pp];
    }
    __syncthreads();

    const int w    = tid >> 6;          // p-quarter
    const int lane = tid & 63;
    const int j4   = lane << 2;
    const float* lp = leftT + (size_t)b * PP * NN + j4;

    float4 A0 = {0.f, 0.f, 0.f, 0.f}, A1 = A0, A2 = A0, A3 = A0;
    const int pbase = w * 32;
    #pragma unroll
    for (int g = 0; g < 8; ++g) {
        const int p = pbase + g * 4;
        float4 wo = *(const float4*)&sWo[p];       // broadcast b128
        float4 r0 = *(const float4*)&sR[0][p];
        float4 r1 = *(const float4*)&sR[1][p];
        float4 r2 = *(const float4*)&sR[2][p];
        float4 r3 = *(const float4*)&sR[3][p];
        const float* lpp = lp + (size_t)p * NN;
        float4 l0 = *(const float4*)(lpp);         // coalesced b128
        float4 l1 = *(const float4*)(lpp + NN);
        float4 l2 = *(const float4*)(lpp + 2 * NN);
        float4 l3 = *(const float4*)(lpp + 3 * NN);
        A0 = rfma4(l0, r0.x, wo.x, A0);
        A1 = rfma4(l0, r1.x, wo.x, A1);
        A2 = rfma4(l0, r2.x, wo.x, A2);
        A3 = rfma4(l0, r3.x, wo.x, A3);
        A0 = rfma4(l1, r0.y, wo.y, A0);
        A1 = rfma4(l1, r1.y, wo.y, A1);
        A2 = rfma4(l1, r2.y, wo.y, A2);
        A3 = rfma4(l1, r3.y, wo.y, A3);
        A0 = rfma4(l2, r0.z, wo.z, A0);
        A1 = rfma4(l2, r1.z, wo.z, A1);
        A2 = rfma4(l2, r2.z, wo.z, A2);
        A3 = rfma4(l2, r3.z, wo.z, A3);
        A0 = rfma4(l3, r0.w, wo.w, A0);
        A1 = rfma4(l3, r1.w, wo.w, A1);
        A2 = rfma4(l3, r2.w, wo.w, A2);
        A3 = rfma4(l3, r3.w, wo.w, A3);
    }

    red4[w][lane][0] = A0;
    red4[w][lane][1] = A1;
    red4[w][lane][2] = A2;
    red4[w][lane][3] = A3;
    __syncthreads();

    if (tid < 64) {
        float bov = ld1<BF>(bo, 0);
        #pragma unroll
        for (int i = 0; i < 4; ++i) {
            float4 s0 = red4[0][tid][i];
            float4 s1 = red4[1][tid][i];
            float4 s2 = red4[2][tid][i];
            float4 s3 = red4[3][tid][i];
            float4 s;
            s.x = s0.x + s1.x + s2.x + s3.x + bov;
            s.y = s0.y + s1.y + s2.y + s3.y + bov;
            s.z = s0.z + s1.z + s2.z + s3.z + bov;
            s.w = s0.w + s1.w + s2.w + s3.w + bov;
            st4<BF>(outB, (int)(((size_t)(b * NN + i0 + i)) * NN) + tid * 4, s);
        }
    }
}

extern "C" __global__ void __launch_bounds__(256)
big_kernel(const float* __restrict__ leftT, const float* __restrict__ rightW,
           const void* __restrict__ Wo, const void* __restrict__ bo,
           void* __restrict__ outB, const int* __restrict__ flag)
{
    __shared__ float sR[4][128];
    __shared__ float sWo[128];
    __shared__ float4 red4[4][64][4];
    if (*flag) big_body<true >(leftT, rightW, Wo, bo, outB, sR, sWo, red4);
    else       big_body<false>(leftT, rightW, Wo, bo, outB, sR, sWo, red4);
}

extern "C" void kernel_launch(void* const* d_in, const int* in_sizes, int n_in,
                              void* d_out, int out_size, void* d_ws, size_t ws_size,
                              hipStream_t stream) {
    const int*  sent = (const int*)d_in[0];
    const void* emb  = d_in[1];
    const void* Wl   = d_in[2];
    const void* bl   = d_in[3];
    const void* Wr   = d_in[4];
    const void* Wo   = d_in[5];
    const void* bo   = d_in[6];
    const void* Ws1  = d_in[7];
    const void* bs1  = d_in[8];
    const void* Ws2  = d_in[9];
    const void* bs2  = d_in[10];
    const void* We1  = d_in[11];
    const void* be1  = d_in[12];
    const void* We2  = d_in[13];
    const void* be2  = d_in[14];

    // ws layout (identical to passing R9): [flag 4B pad 1KB][leftT 1MB]
    // [rightW 1MB][WTf 600KB][xf 2048x300 f32]
    int*   flag   = (int*)d_ws;
    float* leftT  = (float*)((char*)d_ws + 1024);
    float* rightW = leftT + (size_t)NB * PP * NN;
    float* WTf    = rightW + (size_t)NB * NN * PP;
    float* xf     = WTf + (size_t)DD * NC;

    hipLaunchKernelGGL(detect_kernel, dim3(1), dim3(64), 0, stream,
                       (const u32*)emb, flag);
    hipLaunchKernelGGL(prep_kernel, dim3(48), dim3(256), 0, stream,
                       Wl, Wr, Ws1, We1, sent, emb, WTf, xf, flag);
    hipLaunchKernelGGL(tok_kernel, dim3(512), dim3(256), 0, stream,
                       WTf, xf, bl, bs1, Ws2, bs2, be1, We2, be2,
                       leftT, rightW, d_out, flag);
    hipLaunchKernelGGL(big_kernel, dim3(512), dim3(256), 0, stream,
                       leftT, rightW, Wo, bo, d_out, flag);
}

// Round 11
// 163.024 us; speedup vs baseline: 1.1182x; 1.1077x over previous
//
#include <hip/hip_runtime.h>

// Problem constants: B=8, N=256, D=300, P=128, V=50001
#define NB 8
#define NN 256
#define DD 300
#define PP 128
#define NC 512                          // concat cols = [Wl|Wr|Ws1|We1]
#define OFF_S (NB * NN * NN)            // 524288  start-head element offset
#define OFF_E (NB * NN * NN + NB * NN)  // 526336  end-head element offset

typedef unsigned short u16;
typedef unsigned int   u32;

__device__ __forceinline__ float bf2f(u16 u) {
    union { u32 i; float f; } v;
    v.i = ((u32)u) << 16;
    return v.f;
}
__device__ __forceinline__ u16 f2bf(float f) {
    union { float f; u32 i; } v;
    v.f = f;
    u32 lsb = (v.i >> 16) & 1u;
    v.i += 0x7fffu + lsb;   // round-to-nearest-even
    return (u16)(v.i >> 16);
}

template<bool BF>
__device__ __forceinline__ float4 ld4(const void* base, int idx) {
    if (BF) {
        ushort4 e = *(const ushort4*)((const u16*)base + idx);
        return make_float4(bf2f(e.x), bf2f(e.y), bf2f(e.z), bf2f(e.w));
    } else {
        return *(const float4*)((const float*)base + idx);
    }
}
template<bool BF>
__device__ __forceinline__ float ld1(const void* base, int idx) {
    return BF ? bf2f(((const u16*)base)[idx]) : ((const float*)base)[idx];
}
template<bool BF>
__device__ __forceinline__ void st1(void* base, int idx, float v) {
    if (BF) ((u16*)base)[idx] = f2bf(v);
    else    ((float*)base)[idx] = v;
}
template<bool BF>
__device__ __forceinline__ void st4(void* base, int idx, float4 v) {
    if (BF) {
        ushort4 o = make_ushort4(f2bf(v.x), f2bf(v.y), f2bf(v.z), f2bf(v.w));
        *(ushort4*)((u16*)base + idx) = o;
    } else {
        *(float4*)((float*)base + idx) = v;
    }
}
// acc += relu(l + r) * w, componentwise over l (r, w scalar)
__device__ __forceinline__ float4 rfma4(float4 l, float r, float w, float4 a) {
    a.x = fmaf(fmaxf(l.x + r, 0.f), w, a.x);
    a.y = fmaf(fmaxf(l.y + r, 0.f), w, a.y);
    a.z = fmaf(fmaxf(l.z + r, 0.f), w, a.z);
    a.w = fmaf(fmaxf(l.w + r, 0.f), w, a.w);
    return a;
}

// ---------------------------------------------------------------------------
// Detector (verbatim from passing R2/R4/R7/R8/R9/R10).
// ---------------------------------------------------------------------------
extern "C" __global__ void detect_kernel(const u32* __restrict__ embU,
                                         int* __restrict__ flag) {
    int lane = threadIdx.x;  // 64 threads
    int cnt = 0;
    for (int i = lane; i < 256; i += 64) {
        u32 w = embU[i];
        union { u32 u; float f; } v;
        v.u = (w & 0xFFFFu) << 16;
        float a = fabsf(v.f);
        if (a == 0.f || (a >= 0.00390625f && a <= 256.f)) cnt++;
    }
    #pragma unroll
    for (int off = 32; off; off >>= 1) cnt += __shfl_down(cnt, off, 64);
    if (lane == 0) *flag = (cnt >= 128) ? 1 : 0;
}

// ---------------------------------------------------------------------------
// prep (verbatim from passing R7/R8): WTf[k][c] = (float)Wcat[c][k].
// ---------------------------------------------------------------------------
template<bool BF>
__device__ __forceinline__ void prep_body(
    const void* __restrict__ Wl, const void* __restrict__ Wr,
    const void* __restrict__ Ws1, const void* __restrict__ We1,
    float* __restrict__ WTf, float (*tile)[301])
{
    const int tid = threadIdx.x;
    const int c0  = blockIdx.x * 32;

    for (int e = tid; e < 32 * 75; e += 256) {       // row-major reads
        int r = e / 75;
        int q = e - r * 75;
        int c = c0 + r;
        const void* src = (c < 128) ? Wl : (c < 256) ? Wr
                        : (c < 384) ? Ws1 : We1;
        float4 f = ld4<BF>(src, (c & 127) * DD + 4 * q);
        tile[r][4 * q + 0] = f.x;
        tile[r][4 * q + 1] = f.y;
        tile[r][4 * q + 2] = f.z;
        tile[r][4 * q + 3] = f.w;
    }
    __syncthreads();
    for (int e = tid; e < 300 * 32; e += 256) {      // k-major writes
        int k = e >> 5;
        int c = e & 31;
        WTf[(size_t)k * NC + c0 + c] = tile[c][k];
    }
}

extern "C" __global__ void __launch_bounds__(256)
prep_kernel(const void* __restrict__ Wl, const void* __restrict__ Wr,
            const void* __restrict__ Ws1, const void* __restrict__ We1,
            float* __restrict__ WTf, const int* __restrict__ flag)
{
    __shared__ float tile[32][301];
    if (*flag) prep_body<true >(Wl, Wr, Ws1, We1, WTf, tile);
    else       prep_body<false>(Wl, Wr, Ws1, We1, WTf, tile);
}

// ---------------------------------------------------------------------------
// tok v5 = R8's LDS-x (proven necessary by the R9/R10 regression) + R9's
// 4-col/thread mapping (proven correct). Grid 256 x 256 thr; block = 8
// tokens. half = tid>>7 -> tokens t0+4h..t0+4h+3 (wave-uniform: waves 0-1
// half 0, waves 2-3 half 1); thread owns cols col4..col4+3.
// Per k per wave: 1 ds_read_b128 broadcast + 1 coalesced float4 weight
// load (1KB/wave) + 16 FMAs. Total waves halved vs R8 -> LDS-pipe issue
// (tok's dominant term) halves.
// ---------------------------------------------------------------------------
template<bool BF>
__device__ __forceinline__ void tok_body(
    const int* __restrict__ sent, const void* __restrict__ emb,
    const float* __restrict__ WTf,
    const void* __restrict__ bl,
    const void* __restrict__ bs1, const void* __restrict__ Ws2,
    const void* __restrict__ bs2,
    const void* __restrict__ be1, const void* __restrict__ We2,
    const void* __restrict__ be2,
    float* __restrict__ leftT, float* __restrict__ rightW,
    void* __restrict__ out, float (*sxT)[8], int* sids)
{
    const int tid = threadIdx.x;
    const int t0  = blockIdx.x * 8;

    if (tid < 8) sids[tid] = sent[t0 + tid];
    __syncthreads();

    // Stage 8 tokens token-minor: sxT[k][t] (R7/R8-passing staging).
    for (int e = tid; e < DD * 8; e += 256) {
        int k = e >> 3, t = e & 7;
        sxT[k][t] = ld1<BF>(emb, sids[t] * DD + k);
    }
    __syncthreads();

    const int half = tid >> 7;            // token group (wave-uniform)
    const int l127 = tid & 127;
    const int col4 = l127 * 4;
    const int tbase = t0 + 4 * half;

    float a0[4] = {0,0,0,0}, a1[4] = {0,0,0,0};
    float a2[4] = {0,0,0,0}, a3[4] = {0,0,0,0};   // acc[token][col]

    const float* wrow = WTf + col4;
    #pragma unroll 4
    for (int k = 0; k < DD; ++k) {
        float4 w = *(const float4*)(wrow + (size_t)k * NC);  // coalesced b128
        float4 x = *(const float4*)&sxT[k][4 * half];        // LDS broadcast
        a0[0] = fmaf(w.x, x.x, a0[0]); a0[1] = fmaf(w.y, x.x, a0[1]);
        a0[2] = fmaf(w.z, x.x, a0[2]); a0[3] = fmaf(w.w, x.x, a0[3]);
        a1[0] = fmaf(w.x, x.y, a1[0]); a1[1] = fmaf(w.y, x.y, a1[1]);
        a1[2] = fmaf(w.z, x.y, a1[2]); a1[3] = fmaf(w.w, x.y, a1[3]);
        a2[0] = fmaf(w.x, x.z, a2[0]); a2[1] = fmaf(w.y, x.z, a2[1]);
        a2[2] = fmaf(w.z, x.z, a2[2]); a2[3] = fmaf(w.w, x.z, a2[3]);
        a3[0] = fmaf(w.x, x.w, a3[0]); a3[1] = fmaf(w.y, x.w, a3[1]);
        a3[2] = fmaf(w.z, x.w, a3[2]); a3[3] = fmaf(w.w, x.w, a3[3]);
    }

    // Epilogue (verbatim from R9, which passed correctness).
    const int m = l127 >> 5;       // matrix id: 0 Wl, 1 Wr, 2 Ws1, 3 We1
    const int p = col4 & 127;      // row within matrix, %4==0

    if (m == 0) {                  // left -> leftT[b][p][j], + bl
        float b[4];
        #pragma unroll
        for (int r = 0; r < 4; ++r) b[r] = ld1<BF>(bl, p + r);
        const int bb = tbase >> 8;
        #pragma unroll
        for (int tt = 0; tt < 4; ++tt) {
            const int jj = (tbase + tt) & 255;
            float* acc = (tt == 0) ? a0 : (tt == 1) ? a1 : (tt == 2) ? a2 : a3;
            #pragma unroll
            for (int r = 0; r < 4; ++r)
                leftT[((size_t)bb * PP + p + r) * NN + jj] = acc[r] + b[r];
        }
    } else if (m == 1) {           // right -> rightW[t][p] (float4)
        #pragma unroll
        for (int tt = 0; tt < 4; ++tt) {
            float* acc = (tt == 0) ? a0 : (tt == 1) ? a1 : (tt == 2) ? a2 : a3;
            *(float4*)(rightW + (size_t)(tbase + tt) * PP + p) =
                make_float4(acc[0], acc[1], acc[2], acc[3]);
        }
    } else {                       // start (m==2) / end (m==3) heads
        const void* h1 = (m == 2) ? bs1 : be1;
        const void* h2 = (m == 2) ? Ws2 : We2;
        const void* h3 = (m == 2) ? bs2 : be2;
        float b1[4], w2[4];
        #pragma unroll
        for (int r = 0; r < 4; ++r) {
            b1[r] = ld1<BF>(h1, p + r);
            w2[r] = ld1<BF>(h2, p + r);
        }
        float v[4];
        #pragma unroll
        for (int tt = 0; tt < 4; ++tt) {
            float* acc = (tt == 0) ? a0 : (tt == 1) ? a1 : (tt == 2) ? a2 : a3;
            float s = 0.f;
            #pragma unroll
            for (int r = 0; r < 4; ++r)
                s += fmaxf(acc[r] + b1[r], 0.f) * w2[r];
            v[tt] = s;
        }
        // Reduce over the 32-thread group (aligned 32-lane shuffle segment).
        #pragma unroll
        for (int off = 16; off; off >>= 1) {
            #pragma unroll
            for (int tt = 0; tt < 4; ++tt)
                v[tt] += __shfl_down(v[tt], off, 32);
        }
        if ((l127 & 31) == 0) {
            float b2 = ld1<BF>(h3, 0);
            int base = (m == 2) ? OFF_S : OFF_E;
            #pragma unroll
            for (int tt = 0; tt < 4; ++tt)
                st1<BF>(out, base + tbase + tt, v[tt] + b2);
        }
    }
}

extern "C" __global__ void __launch_bounds__(256)
tok_kernel(const int* __restrict__ sent, const void* __restrict__ emb,
           const float* __restrict__ WTf,
           const void* __restrict__ bl,
           const void* __restrict__ bs1, const void* __restrict__ Ws2,
           const void* __restrict__ bs2,
           const void* __restrict__ be1, const void* __restrict__ We2,
           const void* __restrict__ be2,
           float* __restrict__ leftT, float* __restrict__ rightW,
           void* __restrict__ out, const int* __restrict__ flag)
{
    __shared__ __align__(16) float sxT[DD][8];
    __shared__ int sids[8];
    if (*flag) {
        tok_body<true >(sent, emb, WTf, bl, bs1, Ws2, bs2, be1, We2, be2,
                        leftT, rightW, out, sxT, sids);
    } else {
        tok_body<false>(sent, emb, WTf, bl, bs1, Ws2, bs2, be1, We2, be2,
                        leftT, rightW, out, sxT, sids);
    }
}

// ---------------------------------------------------------------------------
// big v2 (verbatim from passing R8/R9/R10): lane owns 4 j's, 4
// i-accumulators, wave owns a p-quarter, cross-wave LDS reduction.
// ---------------------------------------------------------------------------
template<bool BF>
__device__ __forceinline__ void big_body(
    const float* __restrict__ leftT, const float* __restrict__ rightW,
    const void* __restrict__ Wo, const void* __restrict__ bo,
    void* __restrict__ outB,
    float (*sR)[128], float* sWo, float4 (*red4)[64][4])
{
    const int tid = threadIdx.x;
    const int b   = blockIdx.x >> 6;
    const int i0  = (blockIdx.x & 63) << 2;

    if (tid < 128) sWo[tid] = ld1<BF>(Wo, tid);
    for (int c = tid; c < 512; c += 256) {
        int i = c >> 7, pp = c & 127;
        sR[i][pp] = rightW[((size_t)(b * NN + i0 + i)) * PP + pp];
    }
    __syncthreads();

    const int w    = tid >> 6;          // p-quarter
    const int lane = tid & 63;
    const int j4   = lane << 2;
    const float* lp = leftT + (size_t)b * PP * NN + j4;

    float4 A0 = {0.f, 0.f, 0.f, 0.f}, A1 = A0, A2 = A0, A3 = A0;
    const int pbase = w * 32;
    #pragma unroll
    for (int g = 0; g < 8; ++g) {
        const int p = pbase + g * 4;
        float4 wo = *(const float4*)&sWo[p];       // broadcast b128
        float4 r0 = *(const float4*)&sR[0][p];
        float4 r1 = *(const float4*)&sR[1][p];
        float4 r2 = *(const float4*)&sR[2][p];
        float4 r3 = *(const float4*)&sR[3][p];
        const float* lpp = lp + (size_t)p * NN;
        float4 l0 = *(const float4*)(lpp);         // coalesced b128
        float4 l1 = *(const float4*)(lpp + NN);
        float4 l2 = *(const float4*)(lpp + 2 * NN);
        float4 l3 = *(const float4*)(lpp + 3 * NN);
        A0 = rfma4(l0, r0.x, wo.x, A0);
        A1 = rfma4(l0, r1.x, wo.x, A1);
        A2 = rfma4(l0, r2.x, wo.x, A2);
        A3 = rfma4(l0, r3.x, wo.x, A3);
        A0 = rfma4(l1, r0.y, wo.y, A0);
        A1 = rfma4(l1, r1.y, wo.y, A1);
        A2 = rfma4(l1, r2.y, wo.y, A2);
        A3 = rfma4(l1, r3.y, wo.y, A3);
        A0 = rfma4(l2, r0.z, wo.z, A0);
        A1 = rfma4(l2, r1.z, wo.z, A1);
        A2 = rfma4(l2, r2.z, wo.z, A2);
        A3 = rfma4(l2, r3.z, wo.z, A3);
        A0 = rfma4(l3, r0.w, wo.w, A0);
        A1 = rfma4(l3, r1.w, wo.w, A1);
        A2 = rfma4(l3, r2.w, wo.w, A2);
        A3 = rfma4(l3, r3.w, wo.w, A3);
    }

    red4[w][lane][0] = A0;
    red4[w][lane][1] = A1;
    red4[w][lane][2] = A2;
    red4[w][lane][3] = A3;
    __syncthreads();

    if (tid < 64) {
        float bov = ld1<BF>(bo, 0);
        #pragma unroll
        for (int i = 0; i < 4; ++i) {
            float4 s0 = red4[0][tid][i];
            float4 s1 = red4[1][tid][i];
            float4 s2 = red4[2][tid][i];
            float4 s3 = red4[3][tid][i];
            float4 s;
            s.x = s0.x + s1.x + s2.x + s3.x + bov;
            s.y = s0.y + s1.y + s2.y + s3.y + bov;
            s.z = s0.z + s1.z + s2.z + s3.z + bov;
            s.w = s0.w + s1.w + s2.w + s3.w + bov;
            st4<BF>(outB, (int)(((size_t)(b * NN + i0 + i)) * NN) + tid * 4, s);
        }
    }
}

extern "C" __global__ void __launch_bounds__(256)
big_kernel(const float* __restrict__ leftT, const float* __restrict__ rightW,
           const void* __restrict__ Wo, const void* __restrict__ bo,
           void* __restrict__ outB, const int* __restrict__ flag)
{
    __shared__ float sR[4][128];
    __shared__ float sWo[128];
    __shared__ float4 red4[4][64][4];
    if (*flag) big_body<true >(leftT, rightW, Wo, bo, outB, sR, sWo, red4);
    else       big_body<false>(leftT, rightW, Wo, bo, outB, sR, sWo, red4);
}

extern "C" void kernel_launch(void* const* d_in, const int* in_sizes, int n_in,
                              void* d_out, int out_size, void* d_ws, size_t ws_size,
                              hipStream_t stream) {
    const int*  sent = (const int*)d_in[0];
    const void* emb  = d_in[1];
    const void* Wl   = d_in[2];
    const void* bl   = d_in[3];
    const void* Wr   = d_in[4];
    const void* Wo   = d_in[5];
    const void* bo   = d_in[6];
    const void* Ws1  = d_in[7];
    const void* bs1  = d_in[8];
    const void* Ws2  = d_in[9];
    const void* bs2  = d_in[10];
    const void* We1  = d_in[11];
    const void* be1  = d_in[12];
    const void* We2  = d_in[13];
    const void* be2  = d_in[14];

    // ws layout (identical to passing R7/R8): [flag 4B pad 1KB][leftT 1MB]
    // [rightW 1MB][WTf 600KB]
    int*   flag   = (int*)d_ws;
    float* leftT  = (float*)((char*)d_ws + 1024);
    float* rightW = leftT + (size_t)NB * PP * NN;
    float* WTf    = rightW + (size_t)NB * NN * PP;

    hipLaunchKernelGGL(detect_kernel, dim3(1), dim3(64), 0, stream,
                       (const u32*)emb, flag);
    hipLaunchKernelGGL(prep_kernel, dim3(16), dim3(256), 0, stream,
                       Wl, Wr, Ws1, We1, WTf, flag);
    hipLaunchKernelGGL(tok_kernel, dim3(256), dim3(256), 0, stream,
                       sent, emb, WTf, bl, bs1, Ws2, bs2, be1, We2, be2,
                       leftT, rightW, d_out, flag);
    hipLaunchKernelGGL(big_kernel, dim3(512), dim3(256), 0, stream,
                       leftT, rightW, Wo, bo, d_out, flag);
}

// Round 12
// 159.522 us; speedup vs baseline: 1.1427x; 1.0220x over previous
//
#include <hip/hip_runtime.h>

// Problem constants: B=8, N=256, D=300, P=128, V=50001
#define NB 8
#define NN 256
#define DD 300
#define PP 128
#define NC 512                          // concat cols = [Wl|Wr|Ws1|We1]
#define OFF_S (NB * NN * NN)            // 524288  start-head element offset
#define OFF_E (NB * NN * NN + NB * NN)  // 526336  end-head element offset

typedef unsigned short u16;
typedef unsigned int   u32;

__device__ __forceinline__ float bf2f(u16 u) {
    union { u32 i; float f; } v;
    v.i = ((u32)u) << 16;
    return v.f;
}
__device__ __forceinline__ u16 f2bf(float f) {
    union { float f; u32 i; } v;
    v.f = f;
    u32 lsb = (v.i >> 16) & 1u;
    v.i += 0x7fffu + lsb;   // round-to-nearest-even
    return (u16)(v.i >> 16);
}

template<bool BF>
__device__ __forceinline__ float4 ld4(const void* base, int idx) {
    if (BF) {
        ushort4 e = *(const ushort4*)((const u16*)base + idx);
        return make_float4(bf2f(e.x), bf2f(e.y), bf2f(e.z), bf2f(e.w));
    } else {
        return *(const float4*)((const float*)base + idx);
    }
}
template<bool BF>
__device__ __forceinline__ float ld1(const void* base, int idx) {
    return BF ? bf2f(((const u16*)base)[idx]) : ((const float*)base)[idx];
}
template<bool BF>
__device__ __forceinline__ void st1(void* base, int idx, float v) {
    if (BF) ((u16*)base)[idx] = f2bf(v);
    else    ((float*)base)[idx] = v;
}
template<bool BF>
__device__ __forceinline__ void st4(void* base, int idx, float4 v) {
    if (BF) {
        ushort4 o = make_ushort4(f2bf(v.x), f2bf(v.y), f2bf(v.z), f2bf(v.w));
        *(ushort4*)((u16*)base + idx) = o;
    } else {
        *(float4*)((float*)base + idx) = v;
    }
}
// acc += relu(l + r) * w, componentwise over l (r, w scalar)
__device__ __forceinline__ float4 rfma4(float4 l, float r, float w, float4 a) {
    a.x = fmaf(fmaxf(l.x + r, 0.f), w, a.x);
    a.y = fmaf(fmaxf(l.y + r, 0.f), w, a.y);
    a.z = fmaf(fmaxf(l.z + r, 0.f), w, a.z);
    a.w = fmaf(fmaxf(l.w + r, 0.f), w, a.w);
    return a;
}

// ---------------------------------------------------------------------------
// Inline dtype detector (same math as the passing detect_kernel, recomputed
// deterministically per block — removes the separate dispatch + the global
// flag dependency). First 64 threads scan emb's first 256 words; result
// broadcast via LDS. Identical in every block.
// ---------------------------------------------------------------------------
__device__ __forceinline__ int compute_flag(const u32* __restrict__ embU,
                                            int* sflag) {
    const int tid = threadIdx.x;
    if (tid < 64) {
        int cnt = 0;
        for (int i = tid; i < 256; i += 64) {
            u32 w = embU[i];
            union { u32 u; float f; } v;
            v.u = (w & 0xFFFFu) << 16;
            float a = fabsf(v.f);
            if (a == 0.f || (a >= 0.00390625f && a <= 256.f)) cnt++;
        }
        #pragma unroll
        for (int off = 32; off; off >>= 1) cnt += __shfl_down(cnt, off, 64);
        if (tid == 0) *sflag = (cnt >= 128) ? 1 : 0;
    }
    __syncthreads();
    return *sflag;
}

// ---------------------------------------------------------------------------
// prep (body verbatim from passing R7/R8): WTf[k][c] = (float)Wcat[c][k].
// ---------------------------------------------------------------------------
template<bool BF>
__device__ __forceinline__ void prep_body(
    const void* __restrict__ Wl, const void* __restrict__ Wr,
    const void* __restrict__ Ws1, const void* __restrict__ We1,
    float* __restrict__ WTf, float (*tile)[301])
{
    const int tid = threadIdx.x;
    const int c0  = blockIdx.x * 32;

    for (int e = tid; e < 32 * 75; e += 256) {       // row-major reads
        int r = e / 75;
        int q = e - r * 75;
        int c = c0 + r;
        const void* src = (c < 128) ? Wl : (c < 256) ? Wr
                        : (c < 384) ? Ws1 : We1;
        float4 f = ld4<BF>(src, (c & 127) * DD + 4 * q);
        tile[r][4 * q + 0] = f.x;
        tile[r][4 * q + 1] = f.y;
        tile[r][4 * q + 2] = f.z;
        tile[r][4 * q + 3] = f.w;
    }
    __syncthreads();
    for (int e = tid; e < 300 * 32; e += 256) {      // k-major writes
        int k = e >> 5;
        int c = e & 31;
        WTf[(size_t)k * NC + c0 + c] = tile[c][k];
    }
}

extern "C" __global__ void __launch_bounds__(256)
prep_kernel(const void* __restrict__ Wl, const void* __restrict__ Wr,
            const void* __restrict__ Ws1, const void* __restrict__ We1,
            const void* __restrict__ emb, float* __restrict__ WTf)
{
    __shared__ float tile[32][301];
    __shared__ int sflag;
    int flag = compute_flag((const u32*)emb, &sflag);
    if (flag) prep_body<true >(Wl, Wr, Ws1, We1, WTf, tile);
    else      prep_body<false>(Wl, Wr, Ws1, We1, WTf, tile);
}

// ---------------------------------------------------------------------------
// tok (body verbatim from R8, the best-measured round; only delta: unroll 8
// for deeper weight-load pipelining). Grid 512, 4 tokens/block, thread owns
// concat cols (2*tid, 2*tid+1), wave = matrix, x broadcast from LDS
// (proven necessary by the R9/R10 +22us regression).
// ---------------------------------------------------------------------------
template<bool BF>
__device__ __forceinline__ void tok_body(
    const int* __restrict__ sent, const void* __restrict__ emb,
    const float* __restrict__ WTf,
    const void* __restrict__ bl,
    const void* __restrict__ bs1, const void* __restrict__ Ws2,
    const void* __restrict__ bs2,
    const void* __restrict__ be1, const void* __restrict__ We2,
    const void* __restrict__ be2,
    float* __restrict__ leftT, float* __restrict__ rightW,
    void* __restrict__ out, float (*sxT)[4], int* sids)
{
    const int tid = threadIdx.x;
    const int t0  = blockIdx.x * 4;

    if (tid < 4) sids[tid] = sent[t0 + tid];
    __syncthreads();

    // Stage 4 tokens token-minor: sxT[k][t].
    for (int e = tid; e < DD * 4; e += 256) {
        int k = e >> 2, t = e & 3;
        sxT[k][t] = ld1<BF>(emb, sids[t] * DD + k);
    }
    __syncthreads();

    float a0[4], a1[4];                  // acc[token] for cols p0, p1
    #pragma unroll
    for (int t = 0; t < 4; ++t) { a0[t] = 0.f; a1[t] = 0.f; }

    const float* wp = WTf + 2 * tid;
    #pragma unroll 8
    for (int k = 0; k < DD; ++k) {
        float2 w  = *(const float2*)(wp + (size_t)k * NC);  // coalesced
        float4 xa = *(const float4*)&sxT[k][0];             // LDS broadcast
        a0[0] = fmaf(xa.x, w.x, a0[0]); a1[0] = fmaf(xa.x, w.y, a1[0]);
        a0[1] = fmaf(xa.y, w.x, a0[1]); a1[1] = fmaf(xa.y, w.y, a1[1]);
        a0[2] = fmaf(xa.z, w.x, a0[2]); a1[2] = fmaf(xa.z, w.y, a1[2]);
        a0[3] = fmaf(xa.w, w.x, a0[3]); a1[3] = fmaf(xa.w, w.y, a1[3]);
    }

    const int wv = tid >> 6;     // matrix id (wave-uniform)
    const int l  = tid & 63;
    const int p0 = 2 * l, p1 = p0 + 1;

    if (wv == 0) {               // left = x@Wl.T + bl -> leftT[b][p][j]
        float b0 = ld1<BF>(bl, p0), b1 = ld1<BF>(bl, p1);
        #pragma unroll
        for (int t = 0; t < 4; ++t) {
            int tg = t0 + t, bb = tg >> 8, jj = tg & 255;
            leftT[((size_t)bb * PP + p0) * NN + jj] = a0[t] + b0;
            leftT[((size_t)bb * PP + p1) * NN + jj] = a1[t] + b1;
        }
    } else if (wv == 1) {        // right = x@Wr.T -> rightW[t][p]
        #pragma unroll
        for (int t = 0; t < 4; ++t) {
            rightW[(size_t)(t0 + t) * PP + p0] = a0[t];
            rightW[(size_t)(t0 + t) * PP + p1] = a1[t];
        }
    } else {                     // start (wv==2) / end (wv==3) heads
        const void* h1 = (wv == 2) ? bs1 : be1;
        const void* h2 = (wv == 2) ? Ws2 : We2;
        const void* h3 = (wv == 2) ? bs2 : be2;
        float b0 = ld1<BF>(h1, p0), b1 = ld1<BF>(h1, p1);
        float w0 = ld1<BF>(h2, p0), w1 = ld1<BF>(h2, p1);
        float v[4];
        #pragma unroll
        for (int t = 0; t < 4; ++t)
            v[t] = fmaxf(a0[t] + b0, 0.f) * w0 + fmaxf(a1[t] + b1, 0.f) * w1;
        #pragma unroll
        for (int off = 32; off; off >>= 1) {
            #pragma unroll
            for (int t = 0; t < 4; ++t) v[t] += __shfl_down(v[t], off, 64);
        }
        if (l == 0) {
            float b2 = ld1<BF>(h3, 0);
            int base = (wv == 2) ? OFF_S : OFF_E;
            #pragma unroll
            for (int t = 0; t < 4; ++t)
                st1<BF>(out, base + t0 + t, v[t] + b2);
        }
    }
}

extern "C" __global__ void __launch_bounds__(256)
tok_kernel(const int* __restrict__ sent, const void* __restrict__ emb,
           const float* __restrict__ WTf,
           const void* __restrict__ bl,
           const void* __restrict__ bs1, const void* __restrict__ Ws2,
           const void* __restrict__ bs2,
           const void* __restrict__ be1, const void* __restrict__ We2,
           const void* __restrict__ be2,
           float* __restrict__ leftT, float* __restrict__ rightW,
           void* __restrict__ out)
{
    __shared__ __align__(16) float sxT[DD][4];
    __shared__ int sids[4];
    __shared__ int sflag;
    int flag = compute_flag((const u32*)emb, &sflag);
    if (flag) {
        tok_body<true >(sent, emb, WTf, bl, bs1, Ws2, bs2, be1, We2, be2,
                        leftT, rightW, out, sxT, sids);
    } else {
        tok_body<false>(sent, emb, WTf, bl, bs1, Ws2, bs2, be1, We2, be2,
                        leftT, rightW, out, sxT, sids);
    }
}

// ---------------------------------------------------------------------------
// big v2 (body verbatim from passing R8-R11): lane owns 4 j's, 4
// i-accumulators, wave owns a p-quarter, cross-wave LDS reduction.
// ---------------------------------------------------------------------------
template<bool BF>
__device__ __forceinline__ void big_body(
    const float* __restrict__ leftT, const float* __restrict__ rightW,
    const void* __restrict__ Wo, const void* __restrict__ bo,
    void* __restrict__ outB,
    float (*sR)[128], float* sWo, float4 (*red4)[64][4])
{
    const int tid = threadIdx.x;
    const int b   = blockIdx.x >> 6;
    const int i0  = (blockIdx.x & 63) << 2;

    if (tid < 128) sWo[tid] = ld1<BF>(Wo, tid);
    for (int c = tid; c < 512; c += 256) {
        int i = c >> 7, pp = c & 127;
        sR[i][pp] = rightW[((size_t)(b * NN + i0 + i)) * PP + pp];
    }
    __syncthreads();

    const int w    = tid >> 6;          // p-quarter
    const int lane = tid & 63;
    const int j4   = lane << 2;
    const float* lp = leftT + (size_t)b * PP * NN + j4;

    float4 A0 = {0.f, 0.f, 0.f, 0.f}, A1 = A0, A2 = A0, A3 = A0;
    const int pbase = w * 32;
    #pragma unroll
    for (int g = 0; g < 8; ++g) {
        const int p = pbase + g * 4;
        float4 wo = *(const float4*)&sWo[p];       // broadcast b128
        float4 r0 = *(const float4*)&sR[0][p];
        float4 r1 = *(const float4*)&sR[1][p];
        float4 r2 = *(const float4*)&sR[2][p];
        float4 r3 = *(const float4*)&sR[3][p];
        const float* lpp = lp + (size_t)p * NN;
        float4 l0 = *(const float4*)(lpp);         // coalesced b128
        float4 l1 = *(const float4*)(lpp + NN);
        float4 l2 = *(const float4*)(lpp + 2 * NN);
        float4 l3 = *(const float4*)(lpp + 3 * NN);
        A0 = rfma4(l0, r0.x, wo.x, A0);
        A1 = rfma4(l0, r1.x, wo.x, A1);
        A2 = rfma4(l0, r2.x, wo.x, A2);
        A3 = rfma4(l0, r3.x, wo.x, A3);
        A0 = rfma4(l1, r0.y, wo.y, A0);
        A1 = rfma4(l1, r1.y, wo.y, A1);
        A2 = rfma4(l1, r2.y, wo.y, A2);
        A3 = rfma4(l1, r3.y, wo.y, A3);
        A0 = rfma4(l2, r0.z, wo.z, A0);
        A1 = rfma4(l2, r1.z, wo.z, A1);
        A2 = rfma4(l2, r2.z, wo.z, A2);
        A3 = rfma4(l2, r3.z, wo.z, A3);
        A0 = rfma4(l3, r0.w, wo.w, A0);
        A1 = rfma4(l3, r1.w, wo.w, A1);
        A2 = rfma4(l3, r2.w, wo.w, A2);
        A3 = rfma4(l3, r3.w, wo.w, A3);
    }

    red4[w][lane][0] = A0;
    red4[w][lane][1] = A1;
    red4[w][lane][2] = A2;
    red4[w][lane][3] = A3;
    __syncthreads();

    if (tid < 64) {
        float bov = ld1<BF>(bo, 0);
        #pragma unroll
        for (int i = 0; i < 4; ++i) {
            float4 s0 = red4[0][tid][i];
            float4 s1 = red4[1][tid][i];
            float4 s2 = red4[2][tid][i];
            float4 s3 = red4[3][tid][i];
            float4 s;
            s.x = s0.x + s1.x + s2.x + s3.x + bov;
            s.y = s0.y + s1.y + s2.y + s3.y + bov;
            s.z = s0.z + s1.z + s2.z + s3.z + bov;
            s.w = s0.w + s1.w + s2.w + s3.w + bov;
            st4<BF>(outB, (int)(((size_t)(b * NN + i0 + i)) * NN) + tid * 4, s);
        }
    }
}

extern "C" __global__ void __launch_bounds__(256)
big_kernel(const float* __restrict__ leftT, const float* __restrict__ rightW,
           const void* __restrict__ Wo, const void* __restrict__ bo,
           const void* __restrict__ emb, void* __restrict__ outB)
{
    __shared__ float sR[4][128];
    __shared__ float sWo[128];
    __shared__ float4 red4[4][64][4];
    __shared__ int sflag;
    int flag = compute_flag((const u32*)emb, &sflag);
    if (flag) big_body<true >(leftT, rightW, Wo, bo, outB, sR, sWo, red4);
    else      big_body<false>(leftT, rightW, Wo, bo, outB, sR, sWo, red4);
}

extern "C" void kernel_launch(void* const* d_in, const int* in_sizes, int n_in,
                              void* d_out, int out_size, void* d_ws, size_t ws_size,
                              hipStream_t stream) {
    const int*  sent = (const int*)d_in[0];
    const void* emb  = d_in[1];
    const void* Wl   = d_in[2];
    const void* bl   = d_in[3];
    const void* Wr   = d_in[4];
    const void* Wo   = d_in[5];
    const void* bo   = d_in[6];
    const void* Ws1  = d_in[7];
    const void* bs1  = d_in[8];
    const void* Ws2  = d_in[9];
    const void* bs2  = d_in[10];
    const void* We1  = d_in[11];
    const void* be1  = d_in[12];
    const void* We2  = d_in[13];
    const void* be2  = d_in[14];

    // ws layout (offsets identical to passing R7/R8/R11; flag slot unused):
    // [1KB pad][leftT 1MB][rightW 1MB][WTf 600KB]
    float* leftT  = (float*)((char*)d_ws + 1024);
    float* rightW = leftT + (size_t)NB * PP * NN;
    float* WTf    = rightW + (size_t)NB * NN * PP;

    hipLaunchKernelGGL(prep_kernel, dim3(16), dim3(256), 0, stream,
                       Wl, Wr, Ws1, We1, emb, WTf);
    hipLaunchKernelGGL(tok_kernel, dim3(512), dim3(256), 0, stream,
                       sent, emb, WTf, bl, bs1, Ws2, bs2, be1, We2, be2,
                       leftT, rightW, d_out);
    hipLaunchKernelGGL(big_kernel, dim3(512), dim3(256), 0, stream,
                       leftT, rightW, Wo, bo, emb, d_out);
}